// Round 3
// baseline (934.571 us; speedup 1.0000x reference)
//
#include <hip/hip_runtime.h>
#include <math.h>

#define NB 512
#define LONGN 1000
#define SHORTN 50
#define TOPKN 50

__device__ __forceinline__ float dot4(float4 a, float4 b) {
  return a.x*b.x + a.y*b.y + a.z*b.z + a.w*b.w;
}

template<int N>
__device__ __forceinline__ float dotN(const float* w, const float* x) {
  const float4* w4 = (const float4*)w;
  const float4* x4 = (const float4*)x;
  float a0 = 0.f, a1 = 0.f, a2 = 0.f, a3 = 0.f;
  #pragma unroll
  for (int k = 0; k < N/4; k += 4) {
    a0 += dot4(w4[k],   x4[k]);
    a1 += dot4(w4[k+1], x4[k+1]);
    a2 += dot4(w4[k+2], x4[k+2]);
    a3 += dot4(w4[k+3], x4[k+3]);
  }
  return (a0 + a1) + (a2 + a3);
}

// dot of 16 float4 (weights in regs) with an LDS/float4 stream
__device__ __forceinline__ float dotw16(const float4* w, const float4* x) {
  float a0=0.f,a1=0.f,a2=0.f,a3=0.f;
  #pragma unroll
  for (int k = 0; k < 16; k += 4) {
    a0 += dot4(w[k],   x[k]);
    a1 += dot4(w[k+1], x[k+1]);
    a2 += dot4(w[k+2], x[k+2]);
    a3 += dot4(w[k+3], x[k+3]);
  }
  return (a0+a1)+(a2+a3);
}

__device__ __forceinline__ float wave_sum(float v) {
  #pragma unroll
  for (int off = 32; off > 0; off >>= 1) v += __shfl_xor(v, off);
  return v;
}
__device__ __forceinline__ float wave_max(float v) {
  #pragma unroll
  for (int off = 32; off > 0; off >>= 1) v = fmaxf(v, __shfl_xor(v, off));
  return v;
}

// ---------------- shared-memory layouts (union via dynamic LDS) ----------------
struct HardSM {
  float A4[64*64];
  float tv[64];
  float te[64];
  float2 cw[64];
  float scores[LONGN];
  int   idsL[LONGN];
  float redE[4*64];
  float vecbuf[64];
  float redV[4];
  int   redI[4];
  float selV[TOPKN];
  int   selI[TOPKN];
};
struct BstSM {
  float xb[SHORTN*64];    // current x
  float kvb[SHORTN*128];  // k,v -> f1
  float qob[SHORTN*68];   // q -> attn-out (padded rows: 17 float4)
};

// ---------------------------------------------------------------------------
// hard+soft search row (one block)
// ---------------------------------------------------------------------------
__device__ void hardsoft_row(
    const int b, HardSM* H,
    const int* __restrict__ target_item_id,
    const int* __restrict__ long_hist_ids,
    const float* __restrict__ item_emb,
    const float* __restrict__ tproj_w, const float* __restrict__ tproj_b,
    const float* __restrict__ attn_w1, const float* __restrict__ attn_b1,
    const float* __restrict__ attn_w2, const float* __restrict__ attn_b2,
    const float* __restrict__ hash_emb,
    const float* __restrict__ sdim_w, const float* __restrict__ sdim_b,
    float* __restrict__ hard_out, float* __restrict__ soft_out)
{
  const int tid = threadIdx.x;
  const int wid = tid >> 6, lane = tid & 63;

  // ---- phase 0 ----
  if (tid < 64) H->tv[tid] = item_emb[target_item_id[b]*64 + tid];
  for (int l = tid; l < LONGN; l += 256) H->idsL[l] = long_hist_ids[b*LONGN + l];
  __syncthreads();
  if (tid < 64) H->te[tid] = tproj_b[tid] + dotN<64>(tproj_w + tid*64, H->tv);
  __syncthreads();
  if (tid < 64) {
    float c = attn_b1[tid] + dotN<64>(attn_w1 + tid*192, H->te);
    H->cw[tid] = make_float2(c, attn_w2[tid]);
  }
  for (int idx = tid; idx < 4096; idx += 256) {
    int i = idx >> 6, j = idx & 63;
    H->A4[idx] = attn_w1[i*192 + 64 + j] + attn_w1[i*192 + 128 + j]*H->te[j];
  }
  __syncthreads();

  // ---- phase 1: scores ----
  const float b2s = attn_b2[0];
  for (int base = 0; base < LONGN; base += 512) {
    const int l0 = base + tid;
    const int l1 = l0 + 256;
    const bool has1 = (l1 < LONGN);
    const int id0 = H->idsL[l0];
    const int id1 = H->idsL[has1 ? l1 : l0];
    const float4* ep0 = (const float4*)(item_emb + id0*64);
    const float4* ep1 = (const float4*)(item_emb + id1*64);
    float4 e0[16], e1[16];
    #pragma unroll
    for (int k = 0; k < 16; ++k) { e0[k] = ep0[k]; e1[k] = ep1[k]; }
    float sc0 = b2s, sc1 = b2s;
    for (int i = 0; i < 64; ++i) {
      const float4* Ar = (const float4*)(H->A4 + i*64);
      float h00=0.f,h01=0.f,h02=0.f,h03=0.f;
      float h10=0.f,h11=0.f,h12=0.f,h13=0.f;
      #pragma unroll
      for (int k = 0; k < 16; k += 4) {
        float4 a0 = Ar[k], a1 = Ar[k+1], a2 = Ar[k+2], a3 = Ar[k+3];
        h00 += dot4(a0, e0[k]);   h01 += dot4(a1, e0[k+1]);
        h02 += dot4(a2, e0[k+2]); h03 += dot4(a3, e0[k+3]);
        h10 += dot4(a0, e1[k]);   h11 += dot4(a1, e1[k+1]);
        h12 += dot4(a2, e1[k+2]); h13 += dot4(a3, e1[k+3]);
      }
      float2 c2 = H->cw[i];
      float hh0 = ((h00+h01)+(h02+h03)) + c2.x;
      float hh1 = ((h10+h11)+(h12+h13)) + c2.x;
      sc0 += c2.y * fmaxf(hh0, 0.f);
      sc1 += c2.y * fmaxf(hh1, 0.f);
    }
    H->scores[l0] = sc0;
    if (has1) H->scores[l1] = sc1;
  }

  // ---- phase 1b: mean of long embeddings ----
  float accE = 0.f;
  for (int l = wid; l < LONGN; l += 4)
    accE += item_emb[H->idsL[l]*64 + lane];
  H->redE[wid*64 + lane] = accE;
  __syncthreads();
  if (wid == 0)
    H->vecbuf[lane] = (H->redE[lane] + H->redE[64+lane] + H->redE[128+lane] + H->redE[192+lane]) * (1.f/1000.f);
  __syncthreads();

  // ---- phase 1c: hash buckets ----
  {
    const int hl = lane >> 4, dd = lane & 15;
    const float* hb = hash_emb + hl*1024*16 + dd;
    float accH = 0.f;
    for (int l = wid; l < LONGN; l += 4)
      accH += hb[(H->idsL[l] & 1023)*16];
    H->redE[wid*64 + lane] = accH;
  }
  __syncthreads();
  if (wid == 0)
    H->vecbuf[lane] += (H->redE[lane] + H->redE[64+lane] + H->redE[128+lane] + H->redE[192+lane]) * (1.f/1000.f);
  __syncthreads();
  if (tid < 64)
    soft_out[b*64 + tid] = sdim_b[tid] + dotN<64>(sdim_w + tid*64, H->vecbuf);

  // ---- phase 2: softmax over 1000 ----
  float mx = -INFINITY;
  for (int l = tid; l < LONGN; l += 256) mx = fmaxf(mx, H->scores[l]);
  mx = wave_max(mx);
  if (lane == 0) H->redV[wid] = mx;
  __syncthreads();
  mx = fmaxf(fmaxf(H->redV[0], H->redV[1]), fmaxf(H->redV[2], H->redV[3]));
  __syncthreads();
  float sm = 0.f;
  for (int l = tid; l < LONGN; l += 256) {
    float a = expf(H->scores[l] - mx);
    H->scores[l] = a;
    sm += a;
  }
  sm = wave_sum(sm);
  if (lane == 0) H->redV[wid] = sm;
  __syncthreads();
  {
    const float inv = 1.f / (H->redV[0] + H->redV[1] + H->redV[2] + H->redV[3]);
    for (int l = tid; l < LONGN; l += 256) H->scores[l] *= inv;
  }
  __syncthreads();

  // ---- phase 3: iterative top-50 ----
  for (int r = 0; r < TOPKN; ++r) {
    float bv = -1.f; int bi = 0x7fffffff;
    for (int l = tid; l < LONGN; l += 256) {
      float v = H->scores[l];
      if (v > bv || (v == bv && l < bi)) { bv = v; bi = l; }
    }
    #pragma unroll
    for (int off = 32; off > 0; off >>= 1) {
      float ov = __shfl_xor(bv, off);
      int   oi = __shfl_xor(bi, off);
      if (ov > bv || (ov == bv && oi < bi)) { bv = ov; bi = oi; }
    }
    if (lane == 0) { H->redV[wid] = bv; H->redI[wid] = bi; }
    __syncthreads();
    if (tid == 0) {
      float fv = H->redV[0]; int fi = H->redI[0];
      #pragma unroll
      for (int w = 1; w < 4; ++w)
        if (H->redV[w] > fv || (H->redV[w] == fv && H->redI[w] < fi)) { fv = H->redV[w]; fi = H->redI[w]; }
      H->selV[r] = fv; H->selI[r] = fi;
      H->scores[fi] = -1.f;
    }
    __syncthreads();
  }

  // ---- phase 4: softmax over 50 ----
  if (wid == 0) {
    float v = (lane < TOPKN) ? H->selV[lane] : -INFINITY;
    float m2 = wave_max(v);
    float e = (lane < TOPKN) ? expf(v - m2) : 0.f;
    float s2 = wave_sum(e);
    if (lane < TOPKN) H->selV[lane] = e / s2;
  }
  __syncthreads();

  // ---- phase 5: hard_repr ----
  float accR = 0.f;
  for (int r = wid; r < TOPKN; r += 4)
    accR += H->selV[r] * item_emb[H->idsL[H->selI[r]]*64 + lane];
  H->redE[wid*64 + lane] = accR;
  __syncthreads();
  if (wid == 0)
    hard_out[b*64 + lane] = H->redE[lane] + H->redE[64+lane] + H->redE[128+lane] + H->redE[192+lane];
}

// ---------------------------------------------------------------------------
// BST transformer row (one block). v3: q precomputed conflict-free, attn-out
// overwrites q slot, out-proj+LN1 and ff2+LN2 fused per-wave in registers.
// ---------------------------------------------------------------------------
__device__ void bst_row(
    const int b, BstSM* S,
    const int* __restrict__ short_ids, const float* __restrict__ item_emb,
    const float* __restrict__ qkv_w, const float* __restrict__ qkv_b,
    const float* __restrict__ out_w, const float* __restrict__ out_b,
    const float* __restrict__ ln1_g, const float* __restrict__ ln1_b,
    const float* __restrict__ ff1_w, const float* __restrict__ ff1_b,
    const float* __restrict__ ff2_w, const float* __restrict__ ff2_b,
    const float* __restrict__ ln2_g, const float* __restrict__ ln2_b,
    float* __restrict__ bst_out)
{
  const int tid = threadIdx.x;
  const int wid = tid >> 6, lane = tid & 63;

  for (int idx = tid; idx < SHORTN*64; idx += 256) {
    int s = idx >> 6, j = idx & 63;
    S->xb[idx] = item_emb[short_ids[b*SHORTN + s]*64 + j];
  }
  __syncthreads();

  for (int l = 0; l < 2; ++l) {
    const float* QW = qkv_w + l*12288;
    const float* QB = qkv_b + l*192;

    // ---- P1a: k,v projection (128 cols x 2 s-halves) ----
    {
      const int c  = tid & 127;
      const int sg = tid >> 7;
      const float* wr = QW + (64 + c)*64;
      float4 w[16];
      #pragma unroll
      for (int k = 0; k < 16; ++k) w[k] = ((const float4*)wr)[k];
      const float bias = QB[64 + c];
      for (int ii = 0; ii < 25; ++ii) {
        const int s = sg*25 + ii;
        S->kvb[s*128 + c] = bias + dotw16(w, (const float4*)(S->xb + s*64));
      }
    }
    // ---- P1b: q projection (64 cols x 4 s-groups) -> qob padded ----
    {
      const int qc = lane;
      const float* wr = QW + qc*64;
      float4 w[16];
      #pragma unroll
      for (int k = 0; k < 16; ++k) w[k] = ((const float4*)wr)[k];
      const float bias = QB[qc];
      #pragma unroll
      for (int ii = 0; ii < 13; ++ii) {
        const int s = wid*13 + ii;
        if (s < SHORTN)
          S->qob[s*68 + qc] = bias + dotw16(w, (const float4*)(S->xb + s*64));
      }
    }
    __syncthreads();

    // ---- attention: thread (h,s); q read once from qob, o written back ----
    if (tid < 4*SHORTN) {
      const int h = tid / SHORTN, s = tid - h*SHORTN;
      float4* qslot = (float4*)(S->qob + s*68 + h*16);
      const float4 qA = qslot[0], qB2 = qslot[1], qC = qslot[2], qD = qslot[3];
      float mxa = -INFINITY;
      for (int t2 = 0; t2 < SHORTN; ++t2) {
        const float4* kp = (const float4*)(S->kvb + t2*128 + h*16);
        float d = dot4(qA,kp[0]) + dot4(qB2,kp[1]) + dot4(qC,kp[2]) + dot4(qD,kp[3]);
        mxa = fmaxf(mxa, d*0.25f);
      }
      float ss = 0.f;
      float4 oa0 = {0,0,0,0}, oa1 = {0,0,0,0}, oa2 = {0,0,0,0}, oa3 = {0,0,0,0};
      for (int t2 = 0; t2 < SHORTN; ++t2) {
        const float4* kp = (const float4*)(S->kvb + t2*128 + h*16);
        float d = dot4(qA,kp[0]) + dot4(qB2,kp[1]) + dot4(qC,kp[2]) + dot4(qD,kp[3]);
        float a = expf(d*0.25f - mxa);
        ss += a;
        const float4* vp = (const float4*)(S->kvb + t2*128 + 64 + h*16);
        float4 v0 = vp[0], v1 = vp[1], v2 = vp[2], v3 = vp[3];
        oa0.x += a*v0.x; oa0.y += a*v0.y; oa0.z += a*v0.z; oa0.w += a*v0.w;
        oa1.x += a*v1.x; oa1.y += a*v1.y; oa1.z += a*v1.z; oa1.w += a*v1.w;
        oa2.x += a*v2.x; oa2.y += a*v2.y; oa2.z += a*v2.z; oa2.w += a*v2.w;
        oa3.x += a*v3.x; oa3.y += a*v3.y; oa3.z += a*v3.z; oa3.w += a*v3.w;
      }
      const float inv = 1.f/ss;
      oa0.x*=inv; oa0.y*=inv; oa0.z*=inv; oa0.w*=inv; qslot[0]=oa0;
      oa1.x*=inv; oa1.y*=inv; oa1.z*=inv; oa1.w*=inv; qslot[1]=oa1;
      oa2.x*=inv; oa2.y*=inv; oa2.z*=inv; oa2.w*=inv; qslot[2]=oa2;
      oa3.x*=inv; oa3.y*=inv; oa3.z*=inv; oa3.w*=inv; qslot[3]=oa3;
    }
    __syncthreads();

    // ---- out-proj + residual + LN1 fused per wave (lane=col, wave owns s) ----
    {
      const float* wr = out_w + l*4096 + lane*64;
      float4 w[16];
      #pragma unroll
      for (int k = 0; k < 16; ++k) w[k] = ((const float4*)wr)[k];
      const float bias = out_b[l*64 + lane];
      const float g = ln1_g[l*64 + lane], bb = ln1_b[l*64 + lane];
      for (int s = wid; s < SHORTN; s += 4) {
        float y = S->xb[s*64 + lane] + bias + dotw16(w, (const float4*)(S->qob + s*68));
        float mean = wave_sum(y) * (1.f/64.f);
        float dv = y - mean;
        float var = wave_sum(dv*dv) * (1.f/64.f);
        S->xb[s*64 + lane] = dv / sqrtf(var + 1e-5f) * g + bb;
      }
    }
    __syncthreads();

    // ---- ff1 + relu -> kvb (128 cols x 2 s-halves) ----
    {
      const int u  = tid & 127;
      const int sg = tid >> 7;
      const float* wr = ff1_w + l*8192 + u*64;
      float4 w[16];
      #pragma unroll
      for (int k = 0; k < 16; ++k) w[k] = ((const float4*)wr)[k];
      const float bias = ff1_b[l*128 + u];
      for (int ii = 0; ii < 25; ++ii) {
        const int s = sg*25 + ii;
        S->kvb[s*128 + u] = fmaxf(bias + dotw16(w, (const float4*)(S->xb + s*64)), 0.f);
      }
    }
    __syncthreads();

    // ---- ff2 + residual + LN2 fused per wave (k-split for register budget) ----
    {
      const float* wr = ff2_w + l*8192 + lane*128;
      float4 w[16];
      #pragma unroll
      for (int k = 0; k < 16; ++k) w[k] = ((const float4*)wr)[k];
      float p[13];
      #pragma unroll
      for (int ii = 0; ii < 13; ++ii) {
        const int s = wid + 4*ii;
        if (s < SHORTN) p[ii] = dotw16(w, (const float4*)(S->kvb + s*128));
      }
      #pragma unroll
      for (int k = 0; k < 16; ++k) w[k] = ((const float4*)wr)[16 + k];
      const float bias = ff2_b[l*64 + lane];
      const float g = ln2_g[l*64 + lane], bb = ln2_b[l*64 + lane];
      #pragma unroll
      for (int ii = 0; ii < 13; ++ii) {
        const int s = wid + 4*ii;
        if (s < SHORTN) {
          float y = S->xb[s*64 + lane] + bias + p[ii]
                  + dotw16(w, (const float4*)(S->kvb + s*128 + 64));
          float mean = wave_sum(y) * (1.f/64.f);
          float dv = y - mean;
          float var = wave_sum(dv*dv) * (1.f/64.f);
          S->xb[s*64 + lane] = dv / sqrtf(var + 1e-5f) * g + bb;
        }
      }
    }
    __syncthreads();
  }

  // mean over sequence
  float acc = 0.f;
  for (int s = wid; s < SHORTN; s += 4) acc += S->xb[s*64 + lane];
  S->kvb[wid*64 + lane] = acc;
  __syncthreads();
  if (wid == 0)
    bst_out[b*64 + lane] = (S->kvb[lane] + S->kvb[64+lane] + S->kvb[128+lane] + S->kvb[192+lane]) * (1.f/50.f);
}

// ---------------------------------------------------------------------------
// Merged kernel: blocks [0,512) = hardsoft rows, [512,1024) = BST rows.
// ---------------------------------------------------------------------------
__global__ __launch_bounds__(256) void fused_kernel(
    const int* __restrict__ target_item_id,
    const int* __restrict__ long_hist_ids,
    const int* __restrict__ short_hist_ids,
    const float* __restrict__ item_emb,
    const float* __restrict__ tproj_w, const float* __restrict__ tproj_b,
    const float* __restrict__ attn_w1, const float* __restrict__ attn_b1,
    const float* __restrict__ attn_w2, const float* __restrict__ attn_b2,
    const float* __restrict__ hash_emb,
    const float* __restrict__ sdim_w, const float* __restrict__ sdim_b,
    const float* __restrict__ qkv_w, const float* __restrict__ qkv_b,
    const float* __restrict__ out_w, const float* __restrict__ out_b,
    const float* __restrict__ ln1_g, const float* __restrict__ ln1_b,
    const float* __restrict__ ff1_w, const float* __restrict__ ff1_b,
    const float* __restrict__ ff2_w, const float* __restrict__ ff2_b,
    const float* __restrict__ ln2_g, const float* __restrict__ ln2_b,
    float* __restrict__ hard_out, float* __restrict__ soft_out,
    float* __restrict__ bst_out)
{
  extern __shared__ __align__(16) char smraw[];
  const int blk = blockIdx.x;
  if (blk < NB) {
    hardsoft_row(blk, (HardSM*)smraw, target_item_id, long_hist_ids, item_emb,
                 tproj_w, tproj_b, attn_w1, attn_b1, attn_w2, attn_b2,
                 hash_emb, sdim_w, sdim_b, hard_out, soft_out);
  } else {
    bst_row(blk - NB, (BstSM*)smraw, short_hist_ids, item_emb, qkv_w, qkv_b,
            out_w, out_b, ln1_g, ln1_b, ff1_w, ff1_b, ff2_w, ff2_b,
            ln2_g, ln2_b, bst_out);
  }
}

// ---------------------------------------------------------------------------
// Fusion MLP. One block per row.
// ---------------------------------------------------------------------------
__global__ __launch_bounds__(256) void fusion_kernel(
    const float* __restrict__ user, const float* __restrict__ hard,
    const float* __restrict__ soft, const float* __restrict__ bst,
    const float* __restrict__ w1, const float* __restrict__ b1,
    const float* __restrict__ w2, const float* __restrict__ b2,
    const float* __restrict__ w3, const float* __restrict__ b3,
    float* __restrict__ out)
{
  __shared__ __align__(16) float comb[256];
  __shared__ __align__(16) float h1[256];
  __shared__ __align__(16) float h2[128];
  const int b = blockIdx.x, tid = threadIdx.x;
  if (tid < 64)       comb[tid] = user[b*64 + tid];
  else if (tid < 128) comb[tid] = hard[b*64 + tid - 64];
  else if (tid < 192) comb[tid] = soft[b*64 + tid - 128];
  else                comb[tid] = bst[b*64 + tid - 192];
  __syncthreads();
  h1[tid] = fmaxf(b1[tid] + dotN<256>(w1 + tid*256, comb), 0.f);
  __syncthreads();
  if (tid < 128) h2[tid] = fmaxf(b2[tid] + dotN<256>(w2 + tid*256, h1), 0.f);
  __syncthreads();
  if (tid < 64) {
    float p = w3[tid]*h2[tid] + w3[tid+64]*h2[tid+64];
    p = wave_sum(p);
    if (tid == 0) out[b] = p + b3[0];
  }
}

extern "C" void kernel_launch(void* const* d_in, const int* in_sizes, int n_in,
                              void* d_out, int out_size, void* d_ws, size_t ws_size,
                              hipStream_t stream) {
  const float* user_features  = (const float*)d_in[0];
  const int*   target_item_id = (const int*)  d_in[1];
  const int*   short_hist_ids = (const int*)  d_in[2];
  const int*   long_hist_ids  = (const int*)  d_in[3];
  const float* item_emb       = (const float*)d_in[4];
  const float* tproj_w  = (const float*)d_in[5];
  const float* tproj_b  = (const float*)d_in[6];
  const float* attn_w1  = (const float*)d_in[7];
  const float* attn_b1  = (const float*)d_in[8];
  const float* attn_w2  = (const float*)d_in[9];
  const float* attn_b2  = (const float*)d_in[10];
  const float* hash_emb = (const float*)d_in[11];
  const float* sdim_w   = (const float*)d_in[12];
  const float* sdim_b   = (const float*)d_in[13];
  const float* tf_qkv_w = (const float*)d_in[14];
  const float* tf_qkv_b = (const float*)d_in[15];
  const float* tf_out_w = (const float*)d_in[16];
  const float* tf_out_b = (const float*)d_in[17];
  const float* tf_ln1_g = (const float*)d_in[18];
  const float* tf_ln1_b = (const float*)d_in[19];
  const float* tf_ff1_w = (const float*)d_in[20];
  const float* tf_ff1_b = (const float*)d_in[21];
  const float* tf_ff2_w = (const float*)d_in[22];
  const float* tf_ff2_b = (const float*)d_in[23];
  const float* tf_ln2_g = (const float*)d_in[24];
  const float* tf_ln2_b = (const float*)d_in[25];
  const float* fus_w1   = (const float*)d_in[26];
  const float* fus_b1   = (const float*)d_in[27];
  const float* fus_w2   = (const float*)d_in[28];
  const float* fus_b2   = (const float*)d_in[29];
  const float* fus_w3   = (const float*)d_in[30];
  const float* fus_b3   = (const float*)d_in[31];

  float* hard = (float*)d_ws;
  float* soft = hard + NB*64;
  float* bst  = soft + NB*64;

  constexpr size_t lds_bytes =
      sizeof(BstSM) > sizeof(HardSM) ? sizeof(BstSM) : sizeof(HardSM);

  fused_kernel<<<2*NB, 256, lds_bytes, stream>>>(
      target_item_id, long_hist_ids, short_hist_ids, item_emb,
      tproj_w, tproj_b, attn_w1, attn_b1, attn_w2, attn_b2,
      hash_emb, sdim_w, sdim_b,
      tf_qkv_w, tf_qkv_b, tf_out_w, tf_out_b, tf_ln1_g, tf_ln1_b,
      tf_ff1_w, tf_ff1_b, tf_ff2_w, tf_ff2_b, tf_ln2_g, tf_ln2_b,
      hard, soft, bst);
  fusion_kernel<<<NB, 256, 0, stream>>>(user_features, hard, soft, bst,
      fus_w1, fus_b1, fus_w2, fus_b2, fus_w3, fus_b3, (float*)d_out);
}

// Round 4
// 622.287 us; speedup vs baseline: 1.5018x; 1.5018x over previous
//
#include <hip/hip_runtime.h>
#include <math.h>

#define NB 512
#define LONGN 1000
#define SHORTN 50
#define TOPKN 50
#define HALFN 500

__device__ __forceinline__ float dot4(float4 a, float4 b) {
  return a.x*b.x + a.y*b.y + a.z*b.z + a.w*b.w;
}

template<int N>
__device__ __forceinline__ float dotN(const float* w, const float* x) {
  const float4* w4 = (const float4*)w;
  const float4* x4 = (const float4*)x;
  float a0 = 0.f, a1 = 0.f, a2 = 0.f, a3 = 0.f;
  #pragma unroll
  for (int k = 0; k < N/4; k += 4) {
    a0 += dot4(w4[k],   x4[k]);
    a1 += dot4(w4[k+1], x4[k+1]);
    a2 += dot4(w4[k+2], x4[k+2]);
    a3 += dot4(w4[k+3], x4[k+3]);
  }
  return (a0 + a1) + (a2 + a3);
}

__device__ __forceinline__ float dotw16(const float4* w, const float4* x) {
  float a0=0.f,a1=0.f,a2=0.f,a3=0.f;
  #pragma unroll
  for (int k = 0; k < 16; k += 4) {
    a0 += dot4(w[k],   x[k]);
    a1 += dot4(w[k+1], x[k+1]);
    a2 += dot4(w[k+2], x[k+2]);
    a3 += dot4(w[k+3], x[k+3]);
  }
  return (a0+a1)+(a2+a3);
}

__device__ __forceinline__ float wave_sum(float v) {
  #pragma unroll
  for (int off = 32; off > 0; off >>= 1) v += __shfl_xor(v, off);
  return v;
}
__device__ __forceinline__ float wave_max(float v) {
  #pragma unroll
  for (int off = 32; off > 0; off >>= 1) v = fmaxf(v, __shfl_xor(v, off));
  return v;
}

// ===========================================================================
// K1: scores for 500 items per block (2 blocks per batch row) + partial
// mean-emb and hash sums. grid = 2*NB.
// ===========================================================================
__global__ __launch_bounds__(256) void hard_scores_kernel(
    const int* __restrict__ target_item_id,
    const int* __restrict__ long_hist_ids,
    const float* __restrict__ item_emb,
    const float* __restrict__ tproj_w, const float* __restrict__ tproj_b,
    const float* __restrict__ attn_w1, const float* __restrict__ attn_b1,
    const float* __restrict__ attn_w2, const float* __restrict__ attn_b2,
    const float* __restrict__ hash_emb,
    float* __restrict__ scores_ws, float* __restrict__ partA,
    float* __restrict__ partH)
{
  __shared__ __align__(16) float A4[64*64];
  __shared__ __align__(16) float tv[64];
  __shared__ __align__(16) float te[64];
  __shared__ __align__(16) float2 cw[64];
  __shared__ int   idsL[HALFN];
  __shared__ __align__(16) float redE[4*64];

  const int bid = blockIdx.x;
  const int b = bid >> 1, half = bid & 1;
  const int base = half * HALFN;
  const int tid = threadIdx.x;
  const int wid = tid >> 6, lane = tid & 63;

  // ---- phase 0 ----
  if (tid < 64) tv[tid] = item_emb[target_item_id[b]*64 + tid];
  for (int l = tid; l < HALFN; l += 256) idsL[l] = long_hist_ids[b*LONGN + base + l];
  __syncthreads();
  if (tid < 64) te[tid] = tproj_b[tid] + dotN<64>(tproj_w + tid*64, tv);
  __syncthreads();
  if (tid < 64) {
    float c = attn_b1[tid] + dotN<64>(attn_w1 + tid*192, te);
    cw[tid] = make_float2(c, attn_w2[tid]);
  }
  for (int idx = tid; idx < 4096; idx += 256) {
    int i = idx >> 6, j = idx & 63;
    A4[idx] = attn_w1[i*192 + 64 + j] + attn_w1[i*192 + 128 + j]*te[j];
  }
  __syncthreads();

  // ---- phase 1: scores (item pair per thread: tid and tid+256) ----
  {
    const float b2s = attn_b2[0];
    const int l0 = tid;
    const int l1 = tid + 256;
    const bool has1 = (l1 < HALFN);
    const int id0 = idsL[l0];
    const int id1 = idsL[has1 ? l1 : l0];
    const float4* ep0 = (const float4*)(item_emb + id0*64);
    const float4* ep1 = (const float4*)(item_emb + id1*64);
    float4 e0[16], e1[16];
    #pragma unroll
    for (int k = 0; k < 16; ++k) { e0[k] = ep0[k]; e1[k] = ep1[k]; }
    float sc0 = b2s, sc1 = b2s;
    for (int i = 0; i < 64; ++i) {
      const float4* Ar = (const float4*)(A4 + i*64);
      float h00=0.f,h01=0.f,h02=0.f,h03=0.f;
      float h10=0.f,h11=0.f,h12=0.f,h13=0.f;
      #pragma unroll
      for (int k = 0; k < 16; k += 4) {
        float4 a0 = Ar[k], a1 = Ar[k+1], a2 = Ar[k+2], a3 = Ar[k+3];
        h00 += dot4(a0, e0[k]);   h01 += dot4(a1, e0[k+1]);
        h02 += dot4(a2, e0[k+2]); h03 += dot4(a3, e0[k+3]);
        h10 += dot4(a0, e1[k]);   h11 += dot4(a1, e1[k+1]);
        h12 += dot4(a2, e1[k+2]); h13 += dot4(a3, e1[k+3]);
      }
      float2 c2 = cw[i];
      float hh0 = ((h00+h01)+(h02+h03)) + c2.x;
      float hh1 = ((h10+h11)+(h12+h13)) + c2.x;
      sc0 += c2.y * fmaxf(hh0, 0.f);
      sc1 += c2.y * fmaxf(hh1, 0.f);
    }
    scores_ws[b*LONGN + base + l0] = sc0;
    if (has1) scores_ws[b*LONGN + base + l1] = sc1;
  }

  // ---- phase 1b: partial sum of long embeddings ----
  float accE = 0.f;
  for (int l = wid; l < HALFN; l += 4)
    accE += item_emb[idsL[l]*64 + lane];
  redE[wid*64 + lane] = accE;
  __syncthreads();
  if (wid == 0)
    partA[bid*64 + lane] = redE[lane] + redE[64+lane] + redE[128+lane] + redE[192+lane];
  __syncthreads();

  // ---- phase 1c: partial hash sums ----
  {
    const int hl = lane >> 4, dd = lane & 15;
    const float* hb = hash_emb + hl*1024*16 + dd;
    float accH = 0.f;
    for (int l = wid; l < HALFN; l += 4)
      accH += hb[(idsL[l] & 1023)*16];
    redE[wid*64 + lane] = accH;
  }
  __syncthreads();
  if (wid == 0)
    partH[bid*64 + lane] = redE[lane] + redE[64+lane] + redE[128+lane] + redE[192+lane];
}

// ===========================================================================
// K2: softmax(1000) + top-50 + re-softmax + hard_repr + soft_repr. grid = NB.
// ===========================================================================
__global__ __launch_bounds__(256) void hard_finish_kernel(
    const int* __restrict__ long_hist_ids,
    const float* __restrict__ item_emb,
    const float* __restrict__ sdim_w, const float* __restrict__ sdim_b,
    const float* __restrict__ scores_ws,
    const float* __restrict__ partA, const float* __restrict__ partH,
    float* __restrict__ hard_out, float* __restrict__ soft_out)
{
  __shared__ __align__(16) float scores[LONGN];
  __shared__ int   idsL[LONGN];
  __shared__ __align__(16) float redE[4*64];
  __shared__ __align__(16) float vecbuf[64];
  __shared__ float redV[4];
  __shared__ int   redI[4];
  __shared__ float selV[TOPKN];
  __shared__ int   selI[TOPKN];

  const int b = blockIdx.x;
  const int tid = threadIdx.x;
  const int wid = tid >> 6, lane = tid & 63;

  for (int l = tid; l < LONGN; l += 256) {
    scores[l] = scores_ws[b*LONGN + l];
    idsL[l] = long_hist_ids[b*LONGN + l];
  }
  __syncthreads();

  // ---- soft_repr ----
  if (tid < 64)
    vecbuf[tid] = (partA[(2*b)*64 + tid] + partA[(2*b+1)*64 + tid]
                 + partH[(2*b)*64 + tid] + partH[(2*b+1)*64 + tid]) * (1.f/1000.f);
  __syncthreads();
  if (tid < 64)
    soft_out[b*64 + tid] = sdim_b[tid] + dotN<64>(sdim_w + tid*64, vecbuf);

  // ---- softmax over 1000 ----
  float mx = -INFINITY;
  for (int l = tid; l < LONGN; l += 256) mx = fmaxf(mx, scores[l]);
  mx = wave_max(mx);
  if (lane == 0) redV[wid] = mx;
  __syncthreads();
  mx = fmaxf(fmaxf(redV[0], redV[1]), fmaxf(redV[2], redV[3]));
  __syncthreads();
  float sm = 0.f;
  for (int l = tid; l < LONGN; l += 256) {
    float a = expf(scores[l] - mx);
    scores[l] = a;
    sm += a;
  }
  sm = wave_sum(sm);
  if (lane == 0) redV[wid] = sm;
  __syncthreads();
  {
    const float inv = 1.f / (redV[0] + redV[1] + redV[2] + redV[3]);
    for (int l = tid; l < LONGN; l += 256) scores[l] *= inv;
  }
  __syncthreads();

  // ---- iterative top-50 ----
  for (int r = 0; r < TOPKN; ++r) {
    float bv = -1.f; int bi = 0x7fffffff;
    for (int l = tid; l < LONGN; l += 256) {
      float v = scores[l];
      if (v > bv || (v == bv && l < bi)) { bv = v; bi = l; }
    }
    #pragma unroll
    for (int off = 32; off > 0; off >>= 1) {
      float ov = __shfl_xor(bv, off);
      int   oi = __shfl_xor(bi, off);
      if (ov > bv || (ov == bv && oi < bi)) { bv = ov; bi = oi; }
    }
    if (lane == 0) { redV[wid] = bv; redI[wid] = bi; }
    __syncthreads();
    if (tid == 0) {
      float fv = redV[0]; int fi = redI[0];
      #pragma unroll
      for (int w = 1; w < 4; ++w)
        if (redV[w] > fv || (redV[w] == fv && redI[w] < fi)) { fv = redV[w]; fi = redI[w]; }
      selV[r] = fv; selI[r] = fi;
      scores[fi] = -1.f;
    }
    __syncthreads();
  }

  // ---- softmax over 50 ----
  if (wid == 0) {
    float v = (lane < TOPKN) ? selV[lane] : -INFINITY;
    float m2 = wave_max(v);
    float e = (lane < TOPKN) ? expf(v - m2) : 0.f;
    float s2 = wave_sum(e);
    if (lane < TOPKN) selV[lane] = e / s2;
  }
  __syncthreads();

  // ---- hard_repr ----
  float accR = 0.f;
  for (int r = wid; r < TOPKN; r += 4)
    accR += selV[r] * item_emb[idsL[selI[r]]*64 + lane];
  redE[wid*64 + lane] = accR;
  __syncthreads();
  if (wid == 0)
    hard_out[b*64 + lane] = redE[lane] + redE[64+lane] + redE[128+lane] + redE[192+lane];
}

// ===========================================================================
// Fallback monolithic hardsoft (R2 version) if ws too small.
// ===========================================================================
__global__ __launch_bounds__(256) void hardsoft_mono_kernel(
    const int* __restrict__ target_item_id,
    const int* __restrict__ long_hist_ids,
    const float* __restrict__ item_emb,
    const float* __restrict__ tproj_w, const float* __restrict__ tproj_b,
    const float* __restrict__ attn_w1, const float* __restrict__ attn_b1,
    const float* __restrict__ attn_w2, const float* __restrict__ attn_b2,
    const float* __restrict__ hash_emb,
    const float* __restrict__ sdim_w, const float* __restrict__ sdim_b,
    float* __restrict__ hard_out, float* __restrict__ soft_out)
{
  __shared__ __align__(16) float A4[64*64];
  __shared__ __align__(16) float tv[64];
  __shared__ __align__(16) float te[64];
  __shared__ __align__(16) float2 cw[64];
  __shared__ __align__(16) float scores[LONGN];
  __shared__ int   idsL[LONGN];
  __shared__ __align__(16) float redE[4*64];
  __shared__ __align__(16) float vecbuf[64];
  __shared__ float redV[4];
  __shared__ int   redI[4];
  __shared__ float selV[TOPKN];
  __shared__ int   selI[TOPKN];

  const int b = blockIdx.x;
  const int tid = threadIdx.x;
  const int wid = tid >> 6, lane = tid & 63;

  if (tid < 64) tv[tid] = item_emb[target_item_id[b]*64 + tid];
  for (int l = tid; l < LONGN; l += 256) idsL[l] = long_hist_ids[b*LONGN + l];
  __syncthreads();
  if (tid < 64) te[tid] = tproj_b[tid] + dotN<64>(tproj_w + tid*64, tv);
  __syncthreads();
  if (tid < 64) {
    float c = attn_b1[tid] + dotN<64>(attn_w1 + tid*192, te);
    cw[tid] = make_float2(c, attn_w2[tid]);
  }
  for (int idx = tid; idx < 4096; idx += 256) {
    int i = idx >> 6, j = idx & 63;
    A4[idx] = attn_w1[i*192 + 64 + j] + attn_w1[i*192 + 128 + j]*te[j];
  }
  __syncthreads();

  const float b2s = attn_b2[0];
  for (int base = 0; base < LONGN; base += 512) {
    const int l0 = base + tid;
    const int l1 = l0 + 256;
    const bool has1 = (l1 < LONGN);
    const int id0 = idsL[l0];
    const int id1 = idsL[has1 ? l1 : l0];
    const float4* ep0 = (const float4*)(item_emb + id0*64);
    const float4* ep1 = (const float4*)(item_emb + id1*64);
    float4 e0[16], e1[16];
    #pragma unroll
    for (int k = 0; k < 16; ++k) { e0[k] = ep0[k]; e1[k] = ep1[k]; }
    float sc0 = b2s, sc1 = b2s;
    for (int i = 0; i < 64; ++i) {
      const float4* Ar = (const float4*)(A4 + i*64);
      float h00=0.f,h01=0.f,h02=0.f,h03=0.f;
      float h10=0.f,h11=0.f,h12=0.f,h13=0.f;
      #pragma unroll
      for (int k = 0; k < 16; k += 4) {
        float4 a0 = Ar[k], a1 = Ar[k+1], a2 = Ar[k+2], a3 = Ar[k+3];
        h00 += dot4(a0, e0[k]);   h01 += dot4(a1, e0[k+1]);
        h02 += dot4(a2, e0[k+2]); h03 += dot4(a3, e0[k+3]);
        h10 += dot4(a0, e1[k]);   h11 += dot4(a1, e1[k+1]);
        h12 += dot4(a2, e1[k+2]); h13 += dot4(a3, e1[k+3]);
      }
      float2 c2 = cw[i];
      float hh0 = ((h00+h01)+(h02+h03)) + c2.x;
      float hh1 = ((h10+h11)+(h12+h13)) + c2.x;
      sc0 += c2.y * fmaxf(hh0, 0.f);
      sc1 += c2.y * fmaxf(hh1, 0.f);
    }
    scores[l0] = sc0;
    if (has1) scores[l1] = sc1;
  }

  float accE = 0.f;
  for (int l = wid; l < LONGN; l += 4)
    accE += item_emb[idsL[l]*64 + lane];
  redE[wid*64 + lane] = accE;
  __syncthreads();
  if (wid == 0)
    vecbuf[lane] = (redE[lane] + redE[64+lane] + redE[128+lane] + redE[192+lane]) * (1.f/1000.f);
  __syncthreads();
  {
    const int hl = lane >> 4, dd = lane & 15;
    const float* hb = hash_emb + hl*1024*16 + dd;
    float accH = 0.f;
    for (int l = wid; l < LONGN; l += 4)
      accH += hb[(idsL[l] & 1023)*16];
    redE[wid*64 + lane] = accH;
  }
  __syncthreads();
  if (wid == 0)
    vecbuf[lane] += (redE[lane] + redE[64+lane] + redE[128+lane] + redE[192+lane]) * (1.f/1000.f);
  __syncthreads();
  if (tid < 64)
    soft_out[b*64 + tid] = sdim_b[tid] + dotN<64>(sdim_w + tid*64, vecbuf);

  float mx = -INFINITY;
  for (int l = tid; l < LONGN; l += 256) mx = fmaxf(mx, scores[l]);
  mx = wave_max(mx);
  if (lane == 0) redV[wid] = mx;
  __syncthreads();
  mx = fmaxf(fmaxf(redV[0], redV[1]), fmaxf(redV[2], redV[3]));
  __syncthreads();
  float sm = 0.f;
  for (int l = tid; l < LONGN; l += 256) {
    float a = expf(scores[l] - mx);
    scores[l] = a;
    sm += a;
  }
  sm = wave_sum(sm);
  if (lane == 0) redV[wid] = sm;
  __syncthreads();
  {
    const float inv = 1.f / (redV[0] + redV[1] + redV[2] + redV[3]);
    for (int l = tid; l < LONGN; l += 256) scores[l] *= inv;
  }
  __syncthreads();

  for (int r = 0; r < TOPKN; ++r) {
    float bv = -1.f; int bi = 0x7fffffff;
    for (int l = tid; l < LONGN; l += 256) {
      float v = scores[l];
      if (v > bv || (v == bv && l < bi)) { bv = v; bi = l; }
    }
    #pragma unroll
    for (int off = 32; off > 0; off >>= 1) {
      float ov = __shfl_xor(bv, off);
      int   oi = __shfl_xor(bi, off);
      if (ov > bv || (ov == bv && oi < bi)) { bv = ov; bi = oi; }
    }
    if (lane == 0) { redV[wid] = bv; redI[wid] = bi; }
    __syncthreads();
    if (tid == 0) {
      float fv = redV[0]; int fi = redI[0];
      #pragma unroll
      for (int w = 1; w < 4; ++w)
        if (redV[w] > fv || (redV[w] == fv && redI[w] < fi)) { fv = redV[w]; fi = redI[w]; }
      selV[r] = fv; selI[r] = fi;
      scores[fi] = -1.f;
    }
    __syncthreads();
  }

  if (wid == 0) {
    float v = (lane < TOPKN) ? selV[lane] : -INFINITY;
    float m2 = wave_max(v);
    float e = (lane < TOPKN) ? expf(v - m2) : 0.f;
    float s2 = wave_sum(e);
    if (lane < TOPKN) selV[lane] = e / s2;
  }
  __syncthreads();

  float accR = 0.f;
  for (int r = wid; r < TOPKN; r += 4)
    accR += selV[r] * item_emb[idsL[selI[r]]*64 + lane];
  redE[wid*64 + lane] = accR;
  __syncthreads();
  if (wid == 0)
    hard_out[b*64 + lane] = redE[lane] + redE[64+lane] + redE[128+lane] + redE[192+lane];
}

// ===========================================================================
// BST transformer (R3 structure, separately compiled). grid = NB.
// ===========================================================================
__global__ __launch_bounds__(256) void bst_kernel(
    const int* __restrict__ short_ids, const float* __restrict__ item_emb,
    const float* __restrict__ qkv_w, const float* __restrict__ qkv_b,
    const float* __restrict__ out_w, const float* __restrict__ out_b,
    const float* __restrict__ ln1_g, const float* __restrict__ ln1_b,
    const float* __restrict__ ff1_w, const float* __restrict__ ff1_b,
    const float* __restrict__ ff2_w, const float* __restrict__ ff2_b,
    const float* __restrict__ ln2_g, const float* __restrict__ ln2_b,
    float* __restrict__ bst_out)
{
  __shared__ __align__(16) float xb[SHORTN*64];    // current x
  __shared__ __align__(16) float kvb[SHORTN*128];  // k,v -> f1
  __shared__ __align__(16) float qob[SHORTN*68];   // q -> attn-out (padded)

  const int b = blockIdx.x, tid = threadIdx.x;
  const int wid = tid >> 6, lane = tid & 63;

  for (int idx = tid; idx < SHORTN*64; idx += 256) {
    int s = idx >> 6, j = idx & 63;
    xb[idx] = item_emb[short_ids[b*SHORTN + s]*64 + j];
  }
  __syncthreads();

  for (int l = 0; l < 2; ++l) {
    const float* QW = qkv_w + l*12288;
    const float* QB = qkv_b + l*192;

    // ---- P1a: k,v projection (128 cols x 2 s-halves) ----
    {
      const int c  = tid & 127;
      const int sg = tid >> 7;
      const float* wr = QW + (64 + c)*64;
      float4 w[16];
      #pragma unroll
      for (int k = 0; k < 16; ++k) w[k] = ((const float4*)wr)[k];
      const float bias = QB[64 + c];
      for (int ii = 0; ii < 25; ++ii) {
        const int s = sg*25 + ii;
        kvb[s*128 + c] = bias + dotw16(w, (const float4*)(xb + s*64));
      }
    }
    // ---- P1b: q projection (lane=col, conflict-free) -> qob padded ----
    {
      const float* wr = QW + lane*64;
      float4 w[16];
      #pragma unroll
      for (int k = 0; k < 16; ++k) w[k] = ((const float4*)wr)[k];
      const float bias = QB[lane];
      #pragma unroll
      for (int ii = 0; ii < 13; ++ii) {
        const int s = wid*13 + ii;
        if (s < SHORTN)
          qob[s*68 + lane] = bias + dotw16(w, (const float4*)(xb + s*64));
      }
    }
    __syncthreads();

    // ---- attention: thread (h,s); q read once, o written back to slot ----
    if (tid < 4*SHORTN) {
      const int h = tid / SHORTN, s = tid - h*SHORTN;
      float4* qslot = (float4*)(qob + s*68 + h*16);
      const float4 qA = qslot[0], qB2 = qslot[1], qC = qslot[2], qD = qslot[3];
      float mxa = -INFINITY;
      for (int t2 = 0; t2 < SHORTN; ++t2) {
        const float4* kp = (const float4*)(kvb + t2*128 + h*16);
        float d = dot4(qA,kp[0]) + dot4(qB2,kp[1]) + dot4(qC,kp[2]) + dot4(qD,kp[3]);
        mxa = fmaxf(mxa, d*0.25f);
      }
      float ss = 0.f;
      float4 oa0 = {0,0,0,0}, oa1 = {0,0,0,0}, oa2 = {0,0,0,0}, oa3 = {0,0,0,0};
      for (int t2 = 0; t2 < SHORTN; ++t2) {
        const float4* kp = (const float4*)(kvb + t2*128 + h*16);
        float d = dot4(qA,kp[0]) + dot4(qB2,kp[1]) + dot4(qC,kp[2]) + dot4(qD,kp[3]);
        float a = expf(d*0.25f - mxa);
        ss += a;
        const float4* vp = (const float4*)(kvb + t2*128 + 64 + h*16);
        float4 v0 = vp[0], v1 = vp[1], v2 = vp[2], v3 = vp[3];
        oa0.x += a*v0.x; oa0.y += a*v0.y; oa0.z += a*v0.z; oa0.w += a*v0.w;
        oa1.x += a*v1.x; oa1.y += a*v1.y; oa1.z += a*v1.z; oa1.w += a*v1.w;
        oa2.x += a*v2.x; oa2.y += a*v2.y; oa2.z += a*v2.z; oa2.w += a*v2.w;
        oa3.x += a*v3.x; oa3.y += a*v3.y; oa3.z += a*v3.z; oa3.w += a*v3.w;
      }
      const float inv = 1.f/ss;
      oa0.x*=inv; oa0.y*=inv; oa0.z*=inv; oa0.w*=inv; qslot[0]=oa0;
      oa1.x*=inv; oa1.y*=inv; oa1.z*=inv; oa1.w*=inv; qslot[1]=oa1;
      oa2.x*=inv; oa2.y*=inv; oa2.z*=inv; oa2.w*=inv; qslot[2]=oa2;
      oa3.x*=inv; oa3.y*=inv; oa3.z*=inv; oa3.w*=inv; qslot[3]=oa3;
    }
    __syncthreads();

    // ---- out-proj + residual + LN1 fused per wave ----
    {
      const float* wr = out_w + l*4096 + lane*64;
      float4 w[16];
      #pragma unroll
      for (int k = 0; k < 16; ++k) w[k] = ((const float4*)wr)[k];
      const float bias = out_b[l*64 + lane];
      const float g = ln1_g[l*64 + lane], bb = ln1_b[l*64 + lane];
      for (int s = wid; s < SHORTN; s += 4) {
        float y = xb[s*64 + lane] + bias + dotw16(w, (const float4*)(qob + s*68));
        float mean = wave_sum(y) * (1.f/64.f);
        float dv = y - mean;
        float var = wave_sum(dv*dv) * (1.f/64.f);
        xb[s*64 + lane] = dv / sqrtf(var + 1e-5f) * g + bb;
      }
    }
    __syncthreads();

    // ---- ff1 + relu -> kvb ----
    {
      const int u  = tid & 127;
      const int sg = tid >> 7;
      const float* wr = ff1_w + l*8192 + u*64;
      float4 w[16];
      #pragma unroll
      for (int k = 0; k < 16; ++k) w[k] = ((const float4*)wr)[k];
      const float bias = ff1_b[l*128 + u];
      for (int ii = 0; ii < 25; ++ii) {
        const int s = sg*25 + ii;
        kvb[s*128 + u] = fmaxf(bias + dotw16(w, (const float4*)(xb + s*64)), 0.f);
      }
    }
    __syncthreads();

    // ---- ff2 + residual + LN2 fused per wave (k-split) ----
    {
      const float* wr = ff2_w + l*8192 + lane*128;
      float4 w[16];
      #pragma unroll
      for (int k = 0; k < 16; ++k) w[k] = ((const float4*)wr)[k];
      float p[13];
      #pragma unroll
      for (int ii = 0; ii < 13; ++ii) {
        const int s = wid + 4*ii;
        if (s < SHORTN) p[ii] = dotw16(w, (const float4*)(kvb + s*128));
      }
      #pragma unroll
      for (int k = 0; k < 16; ++k) w[k] = ((const float4*)wr)[16 + k];
      const float bias = ff2_b[l*64 + lane];
      const float g = ln2_g[l*64 + lane], bb = ln2_b[l*64 + lane];
      #pragma unroll
      for (int ii = 0; ii < 13; ++ii) {
        const int s = wid + 4*ii;
        if (s < SHORTN) {
          float y = xb[s*64 + lane] + bias + p[ii]
                  + dotw16(w, (const float4*)(kvb + s*128 + 64));
          float mean = wave_sum(y) * (1.f/64.f);
          float dv = y - mean;
          float var = wave_sum(dv*dv) * (1.f/64.f);
          xb[s*64 + lane] = dv / sqrtf(var + 1e-5f) * g + bb;
        }
      }
    }
    __syncthreads();
  }

  float acc = 0.f;
  for (int s = wid; s < SHORTN; s += 4) acc += xb[s*64 + lane];
  kvb[wid*64 + lane] = acc;
  __syncthreads();
  if (wid == 0)
    bst_out[b*64 + lane] = (kvb[lane] + kvb[64+lane] + kvb[128+lane] + kvb[192+lane]) * (1.f/50.f);
}

// ===========================================================================
// Fusion MLP. grid = NB.
// ===========================================================================
__global__ __launch_bounds__(256) void fusion_kernel(
    const float* __restrict__ user, const float* __restrict__ hard,
    const float* __restrict__ soft, const float* __restrict__ bst,
    const float* __restrict__ w1, const float* __restrict__ b1,
    const float* __restrict__ w2, const float* __restrict__ b2,
    const float* __restrict__ w3, const float* __restrict__ b3,
    float* __restrict__ out)
{
  __shared__ __align__(16) float comb[256];
  __shared__ __align__(16) float h1[256];
  __shared__ __align__(16) float h2[128];
  const int b = blockIdx.x, tid = threadIdx.x;
  if (tid < 64)       comb[tid] = user[b*64 + tid];
  else if (tid < 128) comb[tid] = hard[b*64 + tid - 64];
  else if (tid < 192) comb[tid] = soft[b*64 + tid - 128];
  else                comb[tid] = bst[b*64 + tid - 192];
  __syncthreads();
  h1[tid] = fmaxf(b1[tid] + dotN<256>(w1 + tid*256, comb), 0.f);
  __syncthreads();
  if (tid < 128) h2[tid] = fmaxf(b2[tid] + dotN<256>(w2 + tid*256, h1), 0.f);
  __syncthreads();
  if (tid < 64) {
    float p = w3[tid]*h2[tid] + w3[tid+64]*h2[tid+64];
    p = wave_sum(p);
    if (tid == 0) out[b] = p + b3[0];
  }
}

extern "C" void kernel_launch(void* const* d_in, const int* in_sizes, int n_in,
                              void* d_out, int out_size, void* d_ws, size_t ws_size,
                              hipStream_t stream) {
  const float* user_features  = (const float*)d_in[0];
  const int*   target_item_id = (const int*)  d_in[1];
  const int*   short_hist_ids = (const int*)  d_in[2];
  const int*   long_hist_ids  = (const int*)  d_in[3];
  const float* item_emb       = (const float*)d_in[4];
  const float* tproj_w  = (const float*)d_in[5];
  const float* tproj_b  = (const float*)d_in[6];
  const float* attn_w1  = (const float*)d_in[7];
  const float* attn_b1  = (const float*)d_in[8];
  const float* attn_w2  = (const float*)d_in[9];
  const float* attn_b2  = (const float*)d_in[10];
  const float* hash_emb = (const float*)d_in[11];
  const float* sdim_w   = (const float*)d_in[12];
  const float* sdim_b   = (const float*)d_in[13];
  const float* tf_qkv_w = (const float*)d_in[14];
  const float* tf_qkv_b = (const float*)d_in[15];
  const float* tf_out_w = (const float*)d_in[16];
  const float* tf_out_b = (const float*)d_in[17];
  const float* tf_ln1_g = (const float*)d_in[18];
  const float* tf_ln1_b = (const float*)d_in[19];
  const float* tf_ff1_w = (const float*)d_in[20];
  const float* tf_ff1_b = (const float*)d_in[21];
  const float* tf_ff2_w = (const float*)d_in[22];
  const float* tf_ff2_b = (const float*)d_in[23];
  const float* tf_ln2_g = (const float*)d_in[24];
  const float* tf_ln2_b = (const float*)d_in[25];
  const float* fus_w1   = (const float*)d_in[26];
  const float* fus_b1   = (const float*)d_in[27];
  const float* fus_w2   = (const float*)d_in[28];
  const float* fus_b2   = (const float*)d_in[29];
  const float* fus_w3   = (const float*)d_in[30];
  const float* fus_b3   = (const float*)d_in[31];

  float* ws = (float*)d_ws;
  float* hard = ws;                    // NB*64
  float* soft = hard + NB*64;          // NB*64
  float* bst  = soft + NB*64;          // NB*64
  float* scores_ws = bst + NB*64;      // NB*1000
  float* partA = scores_ws + NB*LONGN; // NB*2*64
  float* partH = partA + NB*2*64;      // NB*2*64
  const size_t need_bytes = (size_t)(3*NB*64 + NB*LONGN + 2*NB*2*64) * 4;

  if (ws_size >= need_bytes) {
    hard_scores_kernel<<<2*NB, 256, 0, stream>>>(target_item_id, long_hist_ids,
        item_emb, tproj_w, tproj_b, attn_w1, attn_b1, attn_w2, attn_b2,
        hash_emb, scores_ws, partA, partH);
    hard_finish_kernel<<<NB, 256, 0, stream>>>(long_hist_ids, item_emb,
        sdim_w, sdim_b, scores_ws, partA, partH, hard, soft);
  } else {
    hardsoft_mono_kernel<<<NB, 256, 0, stream>>>(target_item_id, long_hist_ids,
        item_emb, tproj_w, tproj_b, attn_w1, attn_b1, attn_w2, attn_b2,
        hash_emb, sdim_w, sdim_b, hard, soft);
  }
  bst_kernel<<<NB, 256, 0, stream>>>(short_hist_ids, item_emb, tf_qkv_w, tf_qkv_b,
      tf_out_w, tf_out_b, tf_ln1_g, tf_ln1_b, tf_ff1_w, tf_ff1_b, tf_ff2_w, tf_ff2_b,
      tf_ln2_g, tf_ln2_b, bst);
  fusion_kernel<<<NB, 256, 0, stream>>>(user_features, hard, soft, bst,
      fus_w1, fus_b1, fus_w2, fus_b2, fus_w3, fus_b3, (float*)d_out);
}